// Round 6
// baseline (279.261 us; speedup 1.0000x reference)
//
#include <hip/hip_runtime.h>

typedef __attribute__((ext_vector_type(8))) short short8;   // 8 bf16 = 4 VGPRs
typedef __attribute__((ext_vector_type(4))) float f32x4;    // MFMA accumulator

#define DEV static __device__ __forceinline__

DEV float bf2f(unsigned short b) { return __uint_as_float(((unsigned)b) << 16); }
DEV unsigned short f2bf(float f) {                          // round-to-nearest-even
  unsigned u = __float_as_uint(f);
  u += 0x7FFFu + ((u >> 16) & 1u);
  return (unsigned short)(u >> 16);
}

// ---------------- prep: f32 -> bf16 casts ----------------
__global__ __launch_bounds__(256) void cast_bf16(const float* __restrict__ src,
                                                 unsigned short* __restrict__ dst, int n4) {
  int i = blockIdx.x * 256 + threadIdx.x;
  if (i >= n4) return;
  float4 f = ((const float4*)src)[i];
  unsigned lo = (unsigned)f2bf(f.x) | ((unsigned)f2bf(f.y) << 16);
  unsigned hi = (unsigned)f2bf(f.z) | ((unsigned)f2bf(f.w) << 16);
  ((uint2*)dst)[i] = make_uint2(lo, hi);
}

// all four 1024x1024 weights in one launch (grid 1024 x 4)
__global__ __launch_bounds__(256) void cast_w4(
    const float* __restrict__ w0, const float* __restrict__ w1,
    const float* __restrict__ w2, const float* __restrict__ w3,
    unsigned short* __restrict__ o0, unsigned short* __restrict__ o1,
    unsigned short* __restrict__ o2, unsigned short* __restrict__ o3) {
  const int which = blockIdx.y;
  const float* s = (which == 0) ? w0 : (which == 1) ? w1 : (which == 2) ? w2 : w3;
  unsigned short* d = (which == 0) ? o0 : (which == 1) ? o1 : (which == 2) ? o2 : o3;
  const int i = blockIdx.x * 256 + threadIdx.x;        // 262144 float4 per weight
  float4 f = ((const float4*)s)[i];
  unsigned lo = (unsigned)f2bf(f.x) | ((unsigned)f2bf(f.y) << 16);
  unsigned hi = (unsigned)f2bf(f.z) | ((unsigned)f2bf(f.w) << 16);
  ((uint2*)d)[i] = make_uint2(lo, hi);
}

// ============== 256x256 8-phase bf16 GEMM, m201-faithful pipeline ==============
// BK=64, 8 waves (2Mx4N), LDS 128KB dbuf, 3-bit XOR swizzle (conflict-free,
// verified r3), depth-3 half-tile prefetch, single vmcnt(6) per K-tile at P4,
// 2 K-tiles per loop iteration (literal buffer indices). NT must be even, >=4.

DEV void stage_half(const unsigned short* __restrict__ g, int row0, int ldk, int kcol,
                    unsigned short* lbuf, int half, int wave, int lane) {
#pragma unroll
  for (int j = 0; j < 2; ++j) {
    const int row_lin = half * 128 + j * 64 + wave * 8 + (lane >> 3);
    const int k_src = (((lane & 7) ^ ((lane >> 3) & 7)) * 8);  // 16B slot ^= row&7
    const unsigned short* src = g + (size_t)(row0 + row_lin) * ldk + kcol + k_src;
    unsigned short* dst = lbuf + half * 8192 + j * 4096 + wave * 512;  // wave-uniform base
    __builtin_amdgcn_global_load_lds((const __attribute__((address_space(1))) void*)src,
                                     (__attribute__((address_space(3))) void*)dst, 16, 0, 0);
  }
}

#define BAR() do { asm volatile("" ::: "memory"); __builtin_amdgcn_s_barrier(); \
                   asm volatile("" ::: "memory"); } while (0)
#define LGKM0() asm volatile("s_waitcnt lgkmcnt(0)" ::: "memory")
#define VMC(n) asm volatile("s_waitcnt vmcnt(" #n ")" ::: "memory")

#define READ_Aset(dst, qr, base) \
  _Pragma("unroll") for (int i4 = 0; i4 < 4; ++i4) \
  _Pragma("unroll") for (int ks = 0; ks < 2; ++ks) { \
    const int r_ = wrow + (qr) * 64 + i4 * 16 + fr; \
    dst[i4][ks] = *(const short8*)((base) + r_ * 128 + ((ks * 64 + kq16) ^ flip)); }

#define READ_Bset(dst, qc, base) \
  _Pragma("unroll") for (int c2 = 0; c2 < 2; ++c2) \
  _Pragma("unroll") for (int ks = 0; ks < 2; ++ks) { \
    const int c_ = wcol + (qc) * 32 + c2 * 16 + fr; \
    dst[c2][ks] = *(const short8*)((base) + c_ * 128 + ((ks * 64 + kq16) ^ flip)); }

#define MMQ(qr, qc, A_, B_) \
  _Pragma("unroll") for (int i4 = 0; i4 < 4; ++i4) \
  _Pragma("unroll") for (int c2 = 0; c2 < 2; ++c2) \
  _Pragma("unroll") for (int ks = 0; ks < 2; ++ks) \
    acc[(qr) * 4 + i4][(qc) * 2 + c2] = __builtin_amdgcn_mfma_f32_16x16x32_bf16( \
        A_[i4][ks], B_[c2][ks], acc[(qr) * 4 + i4][(qc) * 2 + c2], 0, 0, 0);

// Per-tile 4-phase body. Stages (issue-order FIFO): P1: A1(t+1)->NXT;
// P3: B0(t+2)->CUR; P4: B1(t+2),A0(t+2)->CUR. VMC(6)@P4 retires tile t+1's
// 8 loads exactly (3 half-tiles = 6 loads stay in flight). Region safety:
// B-halves of CUR free after P2's barrier (b1 read P2); A-halves after P3.
#define TILE_BODY(tt, CURBUF, NXTBUF) do { \
  const char* Ac = (const char*)&As[CURBUF][0]; \
  const char* Bc = (const char*)&Bs[CURBUF][0]; \
  const int t_ = (tt); \
  const bool h1 = (t_ + 1 < NT), h2 = (t_ + 2 < NT); \
  const int k1 = (t_ + 1) << 6, k2 = (t_ + 2) << 6; \
  /* P1: MM(0,0) */ \
  if (h1) stage_half(A, brow, K, k1, &As[NXTBUF][0], 1, wave, lane); \
  READ_Aset(a, 0, Ac) \
  READ_Bset(b0, 0, Bc) \
  BAR(); LGKM0(); \
  __builtin_amdgcn_s_setprio(1); MMQ(0, 0, a, b0) __builtin_amdgcn_s_setprio(0); \
  BAR(); \
  /* P2: MM(0,1) */ \
  READ_Bset(b1, 1, Bc) \
  BAR(); LGKM0(); \
  __builtin_amdgcn_s_setprio(1); MMQ(0, 1, a, b1) __builtin_amdgcn_s_setprio(0); \
  BAR(); \
  /* P3: MM(1,0) */ \
  if (h2) stage_half(Bt, bcol, K, k2, &Bs[CURBUF][0], 0, wave, lane); \
  READ_Aset(a, 1, Ac) \
  BAR(); LGKM0(); \
  __builtin_amdgcn_s_setprio(1); MMQ(1, 0, a, b0) __builtin_amdgcn_s_setprio(0); \
  BAR(); \
  /* P4: MM(1,1) */ \
  if (h2) { stage_half(Bt, bcol, K, k2, &Bs[CURBUF][0], 1, wave, lane); \
            stage_half(A,  brow, K, k2, &As[CURBUF][0], 0, wave, lane); } \
  BAR(); \
  __builtin_amdgcn_s_setprio(1); MMQ(1, 1, a, b1) __builtin_amdgcn_s_setprio(0); \
  if (h2)      { VMC(6); } \
  else if (h1) { VMC(0); } \
  BAR(); \
} while (0)

template<int EPI>
__global__ __launch_bounds__(512, 2) void gemm256(
    const unsigned short* __restrict__ A, const unsigned short* __restrict__ Bt,
    const float* __restrict__ bias0, const float* __restrict__ bias1,
    const float* __restrict__ bias2,
    float* __restrict__ outF,
    unsigned short* __restrict__ oQ, unsigned short* __restrict__ oK,
    unsigned short* __restrict__ oV,
    int M, int N, int K)
{
  __shared__ alignas(16) unsigned short As[2][16384];   // 64KB: [buf][row*64+k] swizzled
  __shared__ alignas(16) unsigned short Bs[2][16384];   // 64KB
  const int tid  = threadIdx.x;
  const int lane = tid & 63;
  const int wave = tid >> 6;
  const int wr = wave >> 2, wc = wave & 3;    // 2x4 wave grid; wave owns 128x64 output
  const int fr   = lane & 15;
  const int kq16 = (lane >> 4) * 16;          // k-group byte offset
  const int flip = (fr & 7) << 4;             // 3-bit XOR: 16B slot ^= row&7
  // bijective XCD swizzle (grid % 8 == 0 for both uses)
  const int nwg = gridDim.x, cpx = nwg >> 3, orig = blockIdx.x;
  const int logical = (orig & 7) * cpx + (orig >> 3);
  const int ntc = N >> 8;
  const int brow = (logical / ntc) << 8;
  const int bcol = (logical % ntc) << 8;
  const int NT = K >> 6;                      // 16 here (even)
  const int wrow = wr * 128, wcol = wc * 64;

  f32x4 acc[8][4] = {};
  short8 a[4][2], b0[2][2], b1[2][2];

  // prologue: tile0 {A0,A1,B0,B1}, tile1 {B0,B1,A0}; VMC(6) retires tile0's 8
  stage_half(A,  brow, K, 0, &As[0][0], 0, wave, lane);
  stage_half(A,  brow, K, 0, &As[0][0], 1, wave, lane);
  stage_half(Bt, bcol, K, 0, &Bs[0][0], 0, wave, lane);
  stage_half(Bt, bcol, K, 0, &Bs[0][0], 1, wave, lane);
  stage_half(Bt, bcol, K, 64, &Bs[1][0], 0, wave, lane);
  stage_half(Bt, bcol, K, 64, &Bs[1][0], 1, wave, lane);
  stage_half(A,  brow, K, 64, &As[1][0], 0, wave, lane);
  VMC(6);
  BAR();

  for (int t = 0; t < NT; t += 2) {
    TILE_BODY(t,     0, 1);
    TILE_BODY(t + 1, 1, 0);
  }

  // epilogue: C/D layout col=lane&15, row=(lane>>4)*4+q  [m89 verified]
  const int l4 = (lane >> 4) * 4;
#pragma unroll
  for (int rg = 0; rg < 8; ++rg) {
    const int row0 = brow + wrow + rg * 16 + l4;
#pragma unroll
    for (int cg = 0; cg < 4; ++cg) {
      const int col = bcol + wcol + cg * 16 + fr;
      if (EPI == 1) {
        const float bb = bias0[col];
#pragma unroll
        for (int q = 0; q < 4; ++q)
          outF[(size_t)(row0 + q) * N + col] = acc[rg][cg][q] + bb;
      } else {
        const int sel = col >> 10;        // 0=q, 1=k, 2=v
        const int o = col & 1023;
        const float* bp = (sel == 0) ? bias0 : (sel == 1) ? bias1 : bias2;
        unsigned short* dstp = (sel == 0) ? oQ : (sel == 1) ? oK : oV;
        const float bb = bp[o];
        const int h = o >> 6, d = o & 63;
#pragma unroll
        for (int q = 0; q < 4; ++q) {
          const int rr = row0 + q;
          const int bi = rr >> 12, n = rr & 4095;   // tokens-per-batch = 4096
          float val = acc[rg][cg][q] + bb;
          if (sel < 2) val = (val > 0.f) ? (val + 1.f) : __expf(val);  // elu(x)+1
          dstp[((size_t)((bi * 16 + h) * 4096 + n)) * 64 + d] = f2bf(val);
        }
      }
    }
  }
}

// ---------------- kv partials: grid 1024 = 64 bh x 16 chunks of 256 s ----------------
__global__ __launch_bounds__(256) void kv_agg(
    const unsigned short* __restrict__ kbuf, const unsigned short* __restrict__ vbuf,
    float* __restrict__ part_kv, float* __restrict__ part_ks)
{
  __shared__ alignas(16) unsigned short Ksm[16 * 64];
  __shared__ alignas(16) unsigned short Vsm[16 * 64];
  const int blk = blockIdx.x;           // 0..1023
  const int bh = blk >> 4, chunk = blk & 15;
  const int t = threadIdx.x;
  const int d0 = (t >> 4) * 4;          // 16 d-groups
  const int e0 = (t & 15) * 4;          // 16 e-groups
  float acc[4][4] = {};
  float ks[4] = {0.f, 0.f, 0.f, 0.f};
  const size_t base = ((size_t)bh * 4096 + chunk * 256) * 64;
  for (int ss = 0; ss < 256; ss += 16) {
    __syncthreads();
    if (t < 128) *(uint4*)&Ksm[t * 8] = *(const uint4*)&kbuf[base + (size_t)ss * 64 + t * 8];
    else         *(uint4*)&Vsm[(t - 128) * 8] = *(const uint4*)&vbuf[base + (size_t)ss * 64 + (t - 128) * 8];
    __syncthreads();
#pragma unroll
    for (int i = 0; i < 16; ++i) {
      const unsigned ku0 = *(const unsigned*)&Ksm[i * 64 + d0];
      const unsigned ku1 = *(const unsigned*)&Ksm[i * 64 + d0 + 2];
      const unsigned vu0 = *(const unsigned*)&Vsm[i * 64 + e0];
      const unsigned vu1 = *(const unsigned*)&Vsm[i * 64 + e0 + 2];
      const float kk0 = __uint_as_float(ku0 << 16), kk1 = __uint_as_float(ku0 & 0xFFFF0000u);
      const float kk2 = __uint_as_float(ku1 << 16), kk3 = __uint_as_float(ku1 & 0xFFFF0000u);
      const float vv0 = __uint_as_float(vu0 << 16), vv1 = __uint_as_float(vu0 & 0xFFFF0000u);
      const float vv2 = __uint_as_float(vu1 << 16), vv3 = __uint_as_float(vu1 & 0xFFFF0000u);
      ks[0] += kk0; ks[1] += kk1; ks[2] += kk2; ks[3] += kk3;
      acc[0][0] += kk0 * vv0; acc[0][1] += kk0 * vv1; acc[0][2] += kk0 * vv2; acc[0][3] += kk0 * vv3;
      acc[1][0] += kk1 * vv0; acc[1][1] += kk1 * vv1; acc[1][2] += kk1 * vv2; acc[1][3] += kk1 * vv3;
      acc[2][0] += kk2 * vv0; acc[2][1] += kk2 * vv1; acc[2][2] += kk2 * vv2; acc[2][3] += kk2 * vv3;
      acc[3][0] += kk3 * vv0; acc[3][1] += kk3 * vv1; acc[3][2] += kk3 * vv2; acc[3][3] += kk3 * vv3;
    }
  }
#pragma unroll
  for (int r = 0; r < 4; ++r)
    *(float4*)&part_kv[((size_t)blk * 64 + d0 + r) * 64 + e0] =
        make_float4(acc[r][0], acc[r][1], acc[r][2], acc[r][3]);
  if ((t & 15) == 0) {
#pragma unroll
    for (int r = 0; r < 4; ++r) part_ks[blk * 64 + d0 + r] = ks[r];
  }
}

// ---------------- collapse 16 partials -> final kv [64][4096], ksum [64][64] ----------------
__global__ __launch_bounds__(256) void kv_reduce(
    const float* __restrict__ part_kv, const float* __restrict__ part_ks,
    float* __restrict__ kvf, float* __restrict__ ksf)
{
  const int bh = blockIdx.x;            // 64
  const int t = threadIdx.x;
#pragma unroll
  for (int i = 0; i < 16; ++i) {
    const int lin = i * 256 + t;
    float s = 0.f;
#pragma unroll
    for (int c = 0; c < 16; ++c) s += part_kv[((size_t)(bh * 16 + c)) * 4096 + lin];
    kvf[(size_t)bh * 4096 + lin] = s;
  }
  if (t < 64) {
    float s = 0.f;
#pragma unroll
    for (int c = 0; c < 16; ++c) s += part_ks[(bh * 16 + c) * 64 + t];
    ksf[bh * 64 + t] = s;
  }
}

// ---------------- attn[n,e] = (q . kv[:,e]) / (q . ksum + eps) ----------------
__global__ __launch_bounds__(256) void attn_norm(
    const unsigned short* __restrict__ qbuf, const float* __restrict__ kvf,
    const float* __restrict__ ksf, unsigned short* __restrict__ attnb)
{
  __shared__ alignas(16) float kv_lds[4096];
  __shared__ alignas(16) float ks_lds[64];
  __shared__ alignas(16) unsigned short q_lds[4096];
  const int blk = blockIdx.x;
  const int bh = blk >> 6, nt = blk & 63;
  const int b = bh >> 4, h = bh & 15;
  const int t = threadIdx.x;
#pragma unroll
  for (int i = 0; i < 4; ++i) {         // load final kv (L2-hot, 16KB)
    const int lin = i * 1024 + t * 4;
    *(float4*)&kv_lds[lin] = *(const float4*)&kvf[(size_t)bh * 4096 + lin];
  }
  if (t < 64) ks_lds[t] = ksf[bh * 64 + t];
  const size_t qbase = ((size_t)bh * 4096 + nt * 64) * 64;
#pragma unroll
  for (int r = 0; r < 2; ++r)
    *(uint4*)&q_lds[(r * 256 + t) * 8] = *(const uint4*)&qbuf[qbase + (r * 256 + t) * 8];
  __syncthreads();

  const int n_loc = t >> 2, e0 = (t & 3) * 16;
  float num[16] = {};
  float den = 0.f;
  for (int d = 0; d < 64; ++d) {
    const float qd = bf2f(q_lds[n_loc * 64 + d]);
    den += qd * ks_lds[d];
    const float* kvp = &kv_lds[d * 64 + e0];
#pragma unroll
    for (int j = 0; j < 16; ++j) num[j] += qd * kvp[j];
  }
  const float inv = 1.f / (den + 1e-6f);
  unsigned uo[8];
#pragma unroll
  for (int p = 0; p < 8; ++p) {
    const unsigned short a0 = f2bf(num[2 * p] * inv);
    const unsigned short a1 = f2bf(num[2 * p + 1] * inv);
    uo[p] = (unsigned)a0 | ((unsigned)a1 << 16);
  }
  const size_t obase = ((size_t)(b * 4096 + nt * 64 + n_loc)) * 1024 + h * 64 + e0;
  *(uint4*)&attnb[obase]     = make_uint4(uo[0], uo[1], uo[2], uo[3]);
  *(uint4*)&attnb[obase + 8] = make_uint4(uo[4], uo[5], uo[6], uo[7]);
}

extern "C" void kernel_launch(void* const* d_in, const int* in_sizes, int n_in,
                              void* d_out, int out_size, void* d_ws, size_t ws_size,
                              hipStream_t stream)
{
  const float* query = (const float*)d_in[0];
  const float* Wq = (const float*)d_in[1];
  const float* bq = (const float*)d_in[2];
  const float* Wk = (const float*)d_in[3];
  const float* bk = (const float*)d_in[4];
  const float* Wv = (const float*)d_in[5];
  const float* bv = (const float*)d_in[6];
  const float* Wo = (const float*)d_in[7];
  const float* bo = (const float*)d_in[8];
  float* out = (float*)d_out;

  const int M = in_sizes[0] / 1024;               // 16384 rows (B*N)

  // workspace layout (bytes); attnb reuses the dead qbf region after QKV gemm
  char* ws = (char*)d_ws;
  unsigned short* qbf   = (unsigned short*)(ws);              // 33554432 B (dead after QKV)
  unsigned short* attnb = (unsigned short*)(ws);              // reuse
  unsigned short* wqkv  = (unsigned short*)(ws + 33554432);   //  6291456 B (Wq|Wk|Wv rows)
  unsigned short* wobf  = (unsigned short*)(ws + 39845888);   //  2097152 B
  unsigned short* phiq  = (unsigned short*)(ws + 41943040);   // 33554432 B [b,h,n,d]
  unsigned short* phik  = (unsigned short*)(ws + 75497472);   // 33554432 B
  unsigned short* vbf   = (unsigned short*)(ws + 109051904);  // 33554432 B
  float*          pkv   = (float*)(ws + 142606336);           // 16777216 B [1024][64][64]
  float*          pks   = (float*)(ws + 159383552);           //   262144 B [1024][64]
  float*          kvf   = (float*)(ws + 159645696);           //  1048576 B [64][4096]
  float*          ksf   = (float*)(ws + 160694272);           //    16384 B [64][64]

  // 1) casts (2 launches)
  cast_bf16<<<(M * 1024 / 4 + 255) / 256, 256, 0, stream>>>(query, qbf, M * 1024 / 4);
  cast_w4<<<dim3(1024, 4), 256, 0, stream>>>(Wq, Wk, Wv, Wo,
                                             wqkv, wqkv + 1048576, wqkv + 2097152, wobf);

  // 2) fused QKV projection + feature map (grid 768 = 96/XCD)
  gemm256<0><<<dim3((M / 256) * (3072 / 256)), 512, 0, stream>>>(
      qbf, wqkv, bq, bk, bv, nullptr, phiq, phik, vbf, M, 3072, 1024);

  // 3) kv aggregation partials (1024 blocks)
  kv_agg<<<1024, 256, 0, stream>>>(phik, vbf, pkv, pks);

  // 4) collapse partials once
  kv_reduce<<<64, 256, 0, stream>>>(pkv, pks, kvf, ksf);

  // 5) normalized attention -> bf16 [16384,1024] (into old qbf region)
  attn_norm<<<4096, 256, 0, stream>>>(phiq, kvf, ksf, attnb);

  // 6) output projection -> fp32 d_out (grid 256 = 32/XCD)
  gemm256<1><<<dim3((M / 256) * (1024 / 256)), 512, 0, stream>>>(
      attnb, wobf, bo, nullptr, nullptr, out, nullptr, nullptr, nullptr, M, 1024, 1024);
}

// Round 7
// 242.260 us; speedup vs baseline: 1.1527x; 1.1527x over previous
//
#include <hip/hip_runtime.h>

typedef __attribute__((ext_vector_type(8))) short short8;   // 8 bf16 = 4 VGPRs
typedef __attribute__((ext_vector_type(4))) float f32x4;    // MFMA accumulator

#define DEV static __device__ __forceinline__

DEV float bf2f(unsigned short b) { return __uint_as_float(((unsigned)b) << 16); }
DEV unsigned short f2bf(float f) {                          // round-to-nearest-even
  unsigned u = __float_as_uint(f);
  u += 0x7FFFu + ((u >> 16) & 1u);
  return (unsigned short)(u >> 16);
}

// ---------------- prep: f32 -> bf16 casts ----------------
__global__ __launch_bounds__(256) void cast_bf16(const float* __restrict__ src,
                                                 unsigned short* __restrict__ dst, int n4) {
  int i = blockIdx.x * 256 + threadIdx.x;
  if (i >= n4) return;
  float4 f = ((const float4*)src)[i];
  unsigned lo = (unsigned)f2bf(f.x) | ((unsigned)f2bf(f.y) << 16);
  unsigned hi = (unsigned)f2bf(f.z) | ((unsigned)f2bf(f.w) << 16);
  ((uint2*)dst)[i] = make_uint2(lo, hi);
}

__global__ __launch_bounds__(256) void cast_w4(
    const float* __restrict__ w0, const float* __restrict__ w1,
    const float* __restrict__ w2, const float* __restrict__ w3,
    unsigned short* __restrict__ o0, unsigned short* __restrict__ o1,
    unsigned short* __restrict__ o2, unsigned short* __restrict__ o3) {
  const int which = blockIdx.y;
  const float* s = (which == 0) ? w0 : (which == 1) ? w1 : (which == 2) ? w2 : w3;
  unsigned short* d = (which == 0) ? o0 : (which == 1) ? o1 : (which == 2) ? o2 : o3;
  const int i = blockIdx.x * 256 + threadIdx.x;
  float4 f = ((const float4*)s)[i];
  unsigned lo = (unsigned)f2bf(f.x) | ((unsigned)f2bf(f.y) << 16);
  unsigned hi = (unsigned)f2bf(f.z) | ((unsigned)f2bf(f.w) << 16);
  ((uint2*)d)[i] = make_uint2(lo, hi);
}

// ============== 256x256 8-phase bf16 GEMM (r3 schedule — best measured) ==============
DEV void stage_half(const unsigned short* __restrict__ g, int row0, int ldk, int kcol,
                    unsigned short* lbuf, int half, int wave, int lane) {
#pragma unroll
  for (int j = 0; j < 2; ++j) {
    const int row_lin = half * 128 + j * 64 + wave * 8 + (lane >> 3);
    const int k_src = (((lane & 7) ^ ((lane >> 3) & 7)) * 8);  // 16B slot ^= row&7
    const unsigned short* src = g + (size_t)(row0 + row_lin) * ldk + kcol + k_src;
    unsigned short* dst = lbuf + half * 8192 + j * 4096 + wave * 512;  // wave-uniform base
    __builtin_amdgcn_global_load_lds((const __attribute__((address_space(1))) void*)src,
                                     (__attribute__((address_space(3))) void*)dst, 16, 0, 0);
  }
}

#define BAR() do { asm volatile("" ::: "memory"); __builtin_amdgcn_s_barrier(); \
                   asm volatile("" ::: "memory"); } while (0)
#define LGKM0() asm volatile("s_waitcnt lgkmcnt(0)" ::: "memory")
#define VMC(n) asm volatile("s_waitcnt vmcnt(" #n ")" ::: "memory")

#define READ_A(qr) \
  _Pragma("unroll") for (int i4 = 0; i4 < 4; ++i4) \
  _Pragma("unroll") for (int ks = 0; ks < 2; ++ks) { \
    const int r_ = wrow + (qr) * 64 + i4 * 16 + fr; \
    a[i4][ks] = *(const short8*)(Abase + r_ * 128 + ((ks * 64 + kq16) ^ flip)); }

#define READ_B(qc) \
  _Pragma("unroll") for (int c2 = 0; c2 < 2; ++c2) \
  _Pragma("unroll") for (int ks = 0; ks < 2; ++ks) { \
    const int c_ = wcol + (qc) * 32 + c2 * 16 + fr; \
    b[qc][c2][ks] = *(const short8*)(Bbase + c_ * 128 + ((ks * 64 + kq16) ^ flip)); }

#define DO_MFMA(qr, qc) \
  _Pragma("unroll") for (int i4 = 0; i4 < 4; ++i4) \
  _Pragma("unroll") for (int c2 = 0; c2 < 2; ++c2) \
  _Pragma("unroll") for (int ks = 0; ks < 2; ++ks) \
    acc[(qr) * 4 + i4][(qc) * 2 + c2] = __builtin_amdgcn_mfma_f32_16x16x32_bf16( \
        a[i4][ks], b[qc][c2][ks], acc[(qr) * 4 + i4][(qc) * 2 + c2], 0, 0, 0);

template<int EPI>
__global__ __launch_bounds__(512, 2) void gemm256(
    const unsigned short* __restrict__ A, const unsigned short* __restrict__ Bt,
    const float* __restrict__ bias0, const float* __restrict__ bias1,
    const float* __restrict__ bias2,
    float* __restrict__ outF,
    unsigned short* __restrict__ oQ, unsigned short* __restrict__ oK,
    unsigned short* __restrict__ oV,
    int M, int N, int K)
{
  __shared__ alignas(16) unsigned short As[2][16384];
  __shared__ alignas(16) unsigned short Bs[2][16384];
  const int tid  = threadIdx.x;
  const int lane = tid & 63;
  const int wave = tid >> 6;
  const int wr = wave >> 2, wc = wave & 3;
  const int fr   = lane & 15;
  const int kq16 = (lane >> 4) * 16;
  const int flip = (fr & 7) << 4;
  const int nwg = gridDim.x, cpx = nwg >> 3, orig = blockIdx.x;
  const int logical = (orig & 7) * cpx + (orig >> 3);
  const int ntc = N >> 8;
  const int brow = (logical / ntc) << 8;
  const int bcol = (logical % ntc) << 8;
  const int NT = K >> 6;
  const int wrow = wr * 128, wcol = wc * 64;

  f32x4 acc[8][4] = {};
  short8 a[4][2], b[2][2][2];

  // prologue: tile0 {A0,A1,B0,B1}, tile1 {B0,A0}
  stage_half(A,  brow, K, 0, &As[0][0], 0, wave, lane);
  stage_half(A,  brow, K, 0, &As[0][0], 1, wave, lane);
  stage_half(Bt, bcol, K, 0, &Bs[0][0], 0, wave, lane);
  stage_half(Bt, bcol, K, 0, &Bs[0][0], 1, wave, lane);
  if (NT > 1) {
    stage_half(Bt, bcol, K, 64, &Bs[1][0], 0, wave, lane);
    stage_half(A,  brow, K, 64, &As[1][0], 0, wave, lane);
    VMC(4);
  } else {
    VMC(0);
  }
  BAR();

  for (int t = 0; t < NT; ++t) {
    const int cur = t & 1;
    const char* Abase = (const char*)&As[cur][0];
    const char* Bbase = (const char*)&Bs[cur][0];
    const int k1 = (t + 1) << 6, k2 = (t + 2) << 6;

    READ_A(0)
    READ_B(0)
    if (t < NT - 1) stage_half(Bt, bcol, K, k1, &Bs[cur ^ 1][0], 1, wave, lane);
    BAR(); LGKM0();
    __builtin_amdgcn_s_setprio(1);
    DO_MFMA(0, 0)
    __builtin_amdgcn_s_setprio(0);
    BAR();

    READ_B(1)
    if (t < NT - 1) stage_half(A, brow, K, k1, &As[cur ^ 1][0], 1, wave, lane);
    BAR(); LGKM0();
    __builtin_amdgcn_s_setprio(1);
    DO_MFMA(0, 1)
    __builtin_amdgcn_s_setprio(0);
    BAR();

    READ_A(1)
    if (t < NT - 2) stage_half(Bt, bcol, K, k2, &Bs[cur][0], 0, wave, lane);
    BAR(); LGKM0();
    __builtin_amdgcn_s_setprio(1);
    DO_MFMA(1, 0)
    __builtin_amdgcn_s_setprio(0);
    BAR();

    if (t < NT - 2) stage_half(A, brow, K, k2, &As[cur][0], 0, wave, lane);
    BAR();
    __builtin_amdgcn_s_setprio(1);
    DO_MFMA(1, 1)
    __builtin_amdgcn_s_setprio(0);
    if (t < NT - 2)      { VMC(4); }
    else if (t < NT - 1) { VMC(0); }
    BAR();
  }

  // epilogue: C/D layout col=lane&15, row=(lane>>4)*4+q  [m89 verified]
  // EPI==0 now writes row-major [rr][1024] per output matrix (contiguous 32B chunks)
  const int l4 = (lane >> 4) * 4;
#pragma unroll
  for (int rg = 0; rg < 8; ++rg) {
    const int row0 = brow + wrow + rg * 16 + l4;
#pragma unroll
    for (int cg = 0; cg < 4; ++cg) {
      const int col = bcol + wcol + cg * 16 + fr;
      if (EPI == 1) {
        const float bb = bias0[col];
#pragma unroll
        for (int q = 0; q < 4; ++q)
          outF[(size_t)(row0 + q) * N + col] = acc[rg][cg][q] + bb;
      } else {
        const int sel = col >> 10;        // 0=q, 1=k, 2=v
        const int o = col & 1023;
        const float* bp = (sel == 0) ? bias0 : (sel == 1) ? bias1 : bias2;
        unsigned short* dstp = (sel == 0) ? oQ : (sel == 1) ? oK : oV;
        const float bb = bp[o];
#pragma unroll
        for (int q = 0; q < 4; ++q) {
          float val = acc[rg][cg][q] + bb;
          if (sel < 2) val = (val > 0.f) ? (val + 1.f) : __expf(val);  // elu(x)+1
          dstp[(size_t)(row0 + q) * 1024 + o] = f2bf(val);
        }
      }
    }
  }
}

// ---------------- kv partials: grid 1024 = 64 bh x 16 chunks of 256 s ----------------
// inputs now [rr][1024] row-major: row rb+s, cols h*64..h*64+63
__global__ __launch_bounds__(256) void kv_agg(
    const unsigned short* __restrict__ kbuf, const unsigned short* __restrict__ vbuf,
    float* __restrict__ part_kv, float* __restrict__ part_ks)
{
  __shared__ alignas(16) unsigned short Ksm[16 * 64];
  __shared__ alignas(16) unsigned short Vsm[16 * 64];
  const int blk = blockIdx.x;           // 0..1023
  const int bh = blk >> 4, chunk = blk & 15;
  const int bb = bh >> 4, h = bh & 15;
  const int t = threadIdx.x;
  const int d0 = (t >> 4) * 4;
  const int e0 = (t & 15) * 4;
  const int ls = (t & 127) >> 3;        // staging: s row 0..15
  const int lc = (t & 7) * 8;           // staging: 16B chunk
  float acc[4][4] = {};
  float ks[4] = {0.f, 0.f, 0.f, 0.f};
  const int rb = bb * 4096 + chunk * 256;
  for (int ss = 0; ss < 256; ss += 16) {
    __syncthreads();
    const size_t ga = (size_t)(rb + ss + ls) * 1024 + h * 64 + lc;
    if (t < 128) *(uint4*)&Ksm[ls * 64 + lc] = *(const uint4*)&kbuf[ga];
    else         *(uint4*)&Vsm[ls * 64 + lc] = *(const uint4*)&vbuf[ga];
    __syncthreads();
#pragma unroll
    for (int i = 0; i < 16; ++i) {
      const unsigned ku0 = *(const unsigned*)&Ksm[i * 64 + d0];
      const unsigned ku1 = *(const unsigned*)&Ksm[i * 64 + d0 + 2];
      const unsigned vu0 = *(const unsigned*)&Vsm[i * 64 + e0];
      const unsigned vu1 = *(const unsigned*)&Vsm[i * 64 + e0 + 2];
      const float kk0 = __uint_as_float(ku0 << 16), kk1 = __uint_as_float(ku0 & 0xFFFF0000u);
      const float kk2 = __uint_as_float(ku1 << 16), kk3 = __uint_as_float(ku1 & 0xFFFF0000u);
      const float vv0 = __uint_as_float(vu0 << 16), vv1 = __uint_as_float(vu0 & 0xFFFF0000u);
      const float vv2 = __uint_as_float(vu1 << 16), vv3 = __uint_as_float(vu1 & 0xFFFF0000u);
      ks[0] += kk0; ks[1] += kk1; ks[2] += kk2; ks[3] += kk3;
      acc[0][0] += kk0 * vv0; acc[0][1] += kk0 * vv1; acc[0][2] += kk0 * vv2; acc[0][3] += kk0 * vv3;
      acc[1][0] += kk1 * vv0; acc[1][1] += kk1 * vv1; acc[1][2] += kk1 * vv2; acc[1][3] += kk1 * vv3;
      acc[2][0] += kk2 * vv0; acc[2][1] += kk2 * vv1; acc[2][2] += kk2 * vv2; acc[2][3] += kk2 * vv3;
      acc[3][0] += kk3 * vv0; acc[3][1] += kk3 * vv1; acc[3][2] += kk3 * vv2; acc[3][3] += kk3 * vv3;
    }
  }
#pragma unroll
  for (int r = 0; r < 4; ++r)
    *(float4*)&part_kv[((size_t)blk * 64 + d0 + r) * 64 + e0] =
        make_float4(acc[r][0], acc[r][1], acc[r][2], acc[r][3]);
  if ((t & 15) == 0) {
#pragma unroll
    for (int r = 0; r < 4; ++r) part_ks[blk * 64 + d0 + r] = ks[r];
  }
}

// ------- collapse partials -> kvTb bf16 [bh][e][d] + ksum f32 [bh][64] -------
__global__ __launch_bounds__(256) void kv_reduce(
    const float* __restrict__ part_kv, const float* __restrict__ part_ks,
    unsigned short* __restrict__ kvTb, float* __restrict__ ksf)
{
  const int bh = blockIdx.x;            // 64
  const int t = threadIdx.x;
#pragma unroll
  for (int i = 0; i < 16; ++i) {
    const int lin = i * 256 + t;        // lin = d*64+e
    float s = 0.f;
#pragma unroll
    for (int c = 0; c < 16; ++c) s += part_kv[((size_t)(bh * 16 + c)) * 4096 + lin];
    const int d = lin >> 6, e = lin & 63;
    kvTb[(size_t)bh * 4096 + e * 64 + d] = f2bf(s);   // transposed bf16
  }
  if (t < 64) {
    float s = 0.f;
#pragma unroll
    for (int c = 0; c < 16; ++c) s += part_ks[(bh * 16 + c) * 64 + t];
    ksf[bh * 64 + t] = s;
  }
}

// ---------------- attn via MFMA: C = q_tile(256x64) . kvT, normalized ----------------
// A-frags direct from global (q rows, d-contiguous); B-frags from XOR-swizzled LDS kvT;
// den via in-register partial dots + shfl_xor reduce. Same frag geometry as gemm256.
__global__ __launch_bounds__(256) void attn_mfma(
    const unsigned short* __restrict__ qbuf,   // [rr][1024]
    const unsigned short* __restrict__ kvTb,   // [bh][e][d] bf16
    const float* __restrict__ ksf,             // [bh][64]
    unsigned short* __restrict__ attnb)        // [rr][1024]
{
  __shared__ alignas(16) unsigned short kvs[64 * 64];  // swizzled: 16B slot ^= e&7
  __shared__ float ks_lds[64];
  __shared__ float inv_lds[256];
  const int blk = blockIdx.x;           // 1024 = bh*16 + ntile
  const int bh = blk >> 4, ntile = blk & 15;
  const int bb = bh >> 4, h = bh & 15;
  const int t = threadIdx.x;
  const int lane = t & 63, w = t >> 6;
  const int fr = lane & 15, kg = lane >> 4;

  // stage kvT (8KB) with swizzle; ksum
  {
    const unsigned short* src = kvTb + (size_t)bh * 4096;
#pragma unroll
    for (int c = 0; c < 2; ++c) {
      const int slot = t * 2 + c;       // e = slot>>3, 16B slot sl = slot&7
      const int e = slot >> 3, sl = slot & 7;
      short8 v = *(const short8*)&src[e * 64 + sl * 8];
      *(short8*)&kvs[e * 64 + (sl ^ (e & 7)) * 8] = v;
    }
    if (t < 64) ks_lds[t] = ksf[bh * 64 + t];
  }

  // A-frags from global: rows ntile*256 + w*64 + rg*16 + fr, k = ks*32 + kg*8
  const size_t gq = (size_t)bb * 4096 + ntile * 256 + w * 64;
  short8 a[4][2];
#pragma unroll
  for (int rg = 0; rg < 4; ++rg)
#pragma unroll
    for (int ks = 0; ks < 2; ++ks)
      a[rg][ks] = *(const short8*)&qbuf[(gq + rg * 16 + fr) * 1024 + h * 64 + ks * 32 + kg * 8];
  __syncthreads();

  // den per row: lane partial over its 16 k-elems, butterfly over lane bits 4,5
#pragma unroll
  for (int rg = 0; rg < 4; ++rg) {
    float p = 0.f;
#pragma unroll
    for (int ks = 0; ks < 2; ++ks)
#pragma unroll
      for (int j = 0; j < 8; ++j)
        p += bf2f(((const unsigned short*)&a[rg][ks])[j]) * ks_lds[ks * 32 + kg * 8 + j];
    p += __shfl_xor(p, 16);
    p += __shfl_xor(p, 32);
    if (kg == 0) inv_lds[w * 64 + rg * 16 + fr] = 1.f / (p + 1e-6f);
  }

  // B-frags + MFMA
  const int flip = (fr & 7) << 4;
  const int kq16 = kg * 16;
  short8 bf[4][2];
#pragma unroll
  for (int cg = 0; cg < 4; ++cg)
#pragma unroll
    for (int ks = 0; ks < 2; ++ks)
      bf[cg][ks] = *(const short8*)((const char*)kvs + (cg * 16 + fr) * 128 + ((ks * 64 + kq16) ^ flip));
  f32x4 acc[4][4] = {};
#pragma unroll
  for (int rg = 0; rg < 4; ++rg)
#pragma unroll
    for (int cg = 0; cg < 4; ++cg)
#pragma unroll
      for (int ks = 0; ks < 2; ++ks)
        acc[rg][cg] = __builtin_amdgcn_mfma_f32_16x16x32_bf16(a[rg][ks], bf[cg][ks], acc[rg][cg], 0, 0, 0);

  __syncthreads();   // inv_lds visible (also orders kvs reuse; cheap, once)

  // epilogue: row = rg*16 + kg*4 + q, col = cg*16 + fr
#pragma unroll
  for (int rg = 0; rg < 4; ++rg)
#pragma unroll
    for (int cg = 0; cg < 4; ++cg)
#pragma unroll
      for (int q = 0; q < 4; ++q) {
        const int r = rg * 16 + kg * 4 + q;
        const float iv = inv_lds[w * 64 + r];
        attnb[(gq + r) * 1024 + h * 64 + cg * 16 + fr] = f2bf(acc[rg][cg][q] * iv);
      }
}

extern "C" void kernel_launch(void* const* d_in, const int* in_sizes, int n_in,
                              void* d_out, int out_size, void* d_ws, size_t ws_size,
                              hipStream_t stream)
{
  const float* query = (const float*)d_in[0];
  const float* Wq = (const float*)d_in[1];
  const float* bq = (const float*)d_in[2];
  const float* Wk = (const float*)d_in[3];
  const float* bk = (const float*)d_in[4];
  const float* Wv = (const float*)d_in[5];
  const float* bv = (const float*)d_in[6];
  const float* Wo = (const float*)d_in[7];
  const float* bo = (const float*)d_in[8];
  float* out = (float*)d_out;

  const int M = in_sizes[0] / 1024;               // 16384 rows (B*N)

  char* ws = (char*)d_ws;
  unsigned short* qbf   = (unsigned short*)(ws);              // 32MB (dead after QKV)
  unsigned short* attnb = (unsigned short*)(ws);              // reuse
  unsigned short* wqkv  = (unsigned short*)(ws + 33554432);   // 6MB
  unsigned short* wobf  = (unsigned short*)(ws + 39845888);   // 2MB
  unsigned short* phiq  = (unsigned short*)(ws + 41943040);   // 32MB [rr][1024]
  unsigned short* phik  = (unsigned short*)(ws + 75497472);   // 32MB
  unsigned short* vbf   = (unsigned short*)(ws + 109051904);  // 32MB
  float*          pkv   = (float*)(ws + 142606336);           // 16MB [1024][64][64]
  float*          pks   = (float*)(ws + 159383552);           // 256KB
  unsigned short* kvTb  = (unsigned short*)(ws + 159645696);  // 512KB [64][64][64]
  float*          ksf   = (float*)(ws + 160169984);           // 16KB

  cast_bf16<<<(M * 1024 / 4 + 255) / 256, 256, 0, stream>>>(query, qbf, M * 1024 / 4);
  cast_w4<<<dim3(1024, 4), 256, 0, stream>>>(Wq, Wk, Wv, Wo,
                                             wqkv, wqkv + 1048576, wqkv + 2097152, wobf);

  gemm256<0><<<dim3((M / 256) * (3072 / 256)), 512, 0, stream>>>(
      qbf, wqkv, bq, bk, bv, nullptr, phiq, phik, vbf, M, 3072, 1024);

  kv_agg<<<1024, 256, 0, stream>>>(phik, vbf, pkv, pks);
  kv_reduce<<<64, 256, 0, stream>>>(pkv, pks, kvTb, ksf);
  attn_mfma<<<1024, 256, 0, stream>>>(phiq, kvTb, ksf, attnb);

  gemm256<1><<<dim3((M / 256) * (1024 / 256)), 512, 0, stream>>>(
      attnb, wobf, bo, nullptr, nullptr, out, nullptr, nullptr, nullptr, M, 1024, 1024);
}